// Round 19
// baseline (170.042 us; speedup 1.0000x reference)
//
#include <hip/hip_runtime.h>
#include <hip/hip_bf16.h>
#include <math.h>

#define D_MODEL 1024
#define D_STATE 64
#define D_CONV  4
#define D_INNER 2048
#define N_HEADS 8
#define D_HEAD  256
#define BATCH   2
#define SEQ     2048
#define ROWS    (BATCH*SEQ)   /* 4096 */
#define NCHUNK  32            /* SEQ/64 */
#define BCN     1152          /* BC gemm N: 512 B + 512 C + 8 dt + 120 pad */
#define EPS     1e-6f

typedef __attribute__((ext_vector_type(2))) unsigned short ushort2v;
typedef __attribute__((ext_vector_type(4))) unsigned short ushort4v;
typedef __attribute__((ext_vector_type(8))) unsigned short ushort8v;
typedef __attribute__((ext_vector_type(8))) short short8v;
typedef __attribute__((ext_vector_type(4))) float f32x4;

__device__ __forceinline__ float silu_f(float x){ return x / (1.0f + __expf(-x)); }
__device__ __forceinline__ float softplus_f(float x){ return (x > 20.0f) ? x : log1pf(__expf(x)); }
__device__ __forceinline__ float bf2f(unsigned short u){
    union { unsigned int i; float f; } v; v.i = ((unsigned int)u) << 16; return v.f;
}
__device__ __forceinline__ unsigned short f2bf_bits(float f){
    __hip_bfloat16 h = __float2bfloat16(f);
    return *(unsigned short*)&h;
}
__device__ __forceinline__ void gload_lds16(const void* g, void* l){
    __builtin_amdgcn_global_load_lds((const __attribute__((address_space(1))) void*)g,
                                     (__attribute__((address_space(3))) void*)l, 16, 0, 0);
}
__device__ __forceinline__ void vmw(int n){
    switch(n){
        case 0:  asm volatile("s_waitcnt vmcnt(0)"  ::: "memory"); break;
        case 2:  asm volatile("s_waitcnt vmcnt(2)"  ::: "memory"); break;
        case 3:  asm volatile("s_waitcnt vmcnt(3)"  ::: "memory"); break;
        case 4:  asm volatile("s_waitcnt vmcnt(4)"  ::: "memory"); break;
        case 6:  asm volatile("s_waitcnt vmcnt(6)"  ::: "memory"); break;
        default: asm volatile("s_waitcnt vmcnt(0)"  ::: "memory"); break;
    }
}
#define SB() __builtin_amdgcn_sched_barrier(0)

// ---------------- prep: weight conversions + BC/dt assembly + rmsnorm (fused) ----------------
__global__ __launch_bounds__(256) void prep_kernel(const float* __restrict__ in_w,
                                                   const float* __restrict__ out_w,
                                                   const float* __restrict__ B_w,
                                                   const float* __restrict__ C_w,
                                                   const float* __restrict__ dt_w,
                                                   const float* __restrict__ x,
                                                   const float* __restrict__ norm_w,
                                                   unsigned short* __restrict__ inw_bf,
                                                   unsigned short* __restrict__ outw_bf,
                                                   unsigned short* __restrict__ BCw_bf,
                                                   unsigned short* __restrict__ xn){
    __shared__ float red[4];
    int bid = blockIdx.x;
    int tid = threadIdx.x;
    if (bid >= 8448){
        int row = bid - 8448;
        const float4* xr = (const float4*)(x + (size_t)row * D_MODEL);
        float4 a = xr[tid];
        float ss = a.x*a.x + a.y*a.y + a.z*a.z + a.w*a.w;
        #pragma unroll
        for (int i = 1; i < 64; i <<= 1) ss += __shfl_xor(ss, i);
        int lane = tid & 63, wid = tid >> 6;
        if (lane == 0) red[wid] = ss;
        __syncthreads();
        float tot = red[0] + red[1] + red[2] + red[3];
        float scale = rsqrtf(tot * (1.0f / D_MODEL) + EPS);
        float4 wv = ((const float4*)norm_w)[tid];
        ushort4v o;
        o[0] = f2bf_bits(a.x * scale * wv.x);
        o[1] = f2bf_bits(a.y * scale * wv.y);
        o[2] = f2bf_bits(a.z * scale * wv.z);
        o[3] = f2bf_bits(a.w * scale * wv.w);
        ((ushort4v*)(xn + (size_t)row * D_MODEL))[tid] = o;
        return;
    }
    int i = bid * 256 + tid;
    const float* src; unsigned short* dst; int j;
    if (i < 1048576)      { src = in_w;  dst = inw_bf;            j = i; }
    else if (i < 1572864) { src = out_w; dst = outw_bf;           j = i - 1048576; }
    else if (i < 1835008) { src = B_w;   dst = BCw_bf;            j = i - 1572864; }
    else if (i < 2097152) { src = C_w;   dst = BCw_bf + 1048576;  j = i - 1835008; }
    else {
        int k = i - 2097152;
        int drow = k >> 9;
        int col4 = k & 511;
        ushort4v o = {0,0,0,0};
        if (drow < 8){
            float4 v = ((const float4*)(dt_w + (size_t)drow*D_INNER))[col4];
            o[0] = f2bf_bits(v.x); o[1] = f2bf_bits(v.y);
            o[2] = f2bf_bits(v.z); o[3] = f2bf_bits(v.w);
        }
        ((ushort4v*)(BCw_bf + (size_t)(1024 + drow)*D_INNER))[col4] = o;
        return;
    }
    float4 v = ((const float4*)src)[j];
    ushort4v o;
    o[0] = f2bf_bits(v.x); o[1] = f2bf_bits(v.y);
    o[2] = f2bf_bits(v.z); o[3] = f2bf_bits(v.w);
    ((ushort4v*)dst)[j] = o;
}

// ---------------- in_proj GEMM: 512 threads, 256x128 tile, counted-vmcnt 2-deep ----------------
// COMPUTE uses counted-lgkmcnt interleave: MFMAs start after 5 of 8 ds_reads.
__global__ __launch_bounds__(512) void gemm_in512(const unsigned short* __restrict__ A,
                                                  const unsigned short* __restrict__ W,
                                                  unsigned short* __restrict__ Cout0,
                                                  unsigned short* __restrict__ Cout1){
    const int K = D_MODEL;
    __shared__ unsigned short As[2][256*32];
    __shared__ unsigned short Bs[2][128*32];
    int tid = threadIdx.x;
    int bid = blockIdx.x;
    int x = bid & 7;
    int r = bid >> 3;
    int m0 = ((x & 3)*4 + (r >> 4)) * 256;
    int n0 = ((x >> 2)*16 + (r & 15)) * 128;

    int lane = tid & 63;
    int w = tid >> 6;
    int wrow = w >> 1, wcol = w & 1;
    f32x4 acc[4][4];
    #pragma unroll
    for (int i = 0; i < 4; ++i)
        #pragma unroll
        for (int j = 0; j < 4; ++j) acc[i][j] = (f32x4){0.f,0.f,0.f,0.f};

    int g0 = tid >> 3, s0 = tid & 7;
    int swz0 = (s0*16) ^ ((g0&7)<<4);
    int r0 = 2*g0 + (swz0 >> 6);
    int c0e = (swz0 & 63) >> 1;
    const unsigned short* aS0 = A + (size_t)(m0 + r0)*K + c0e;
    const unsigned short* aS1 = aS0 + (size_t)128*K;
    const unsigned short* bS0 = W + (size_t)(n0 + r0)*K + c0e;

    int frow = lane & 15;
    int fkb  = (lane >> 4) * 16;
    int offA[4], offB[4];
    #pragma unroll
    for (int m = 0; m < 4; ++m){
        int rr = wrow*64 + m*16 + frow;
        int lb = (rr&1)*64 + fkb;
        offA[m] = (rr>>1)*128 + (lb ^ (((rr>>1)&7)<<4));
    }
    #pragma unroll
    for (int n = 0; n < 4; ++n){
        int rr = wcol*64 + n*16 + frow;
        int lb = (rr&1)*64 + fkb;
        offB[n] = (rr>>1)*128 + (lb ^ (((rr>>1)&7)<<4));
    }

    #define STAGE(buf, k0) do{ \
        gload_lds16(aS0 + (k0), &As[buf][(size_t)tid*8]); \
        gload_lds16(aS1 + (k0), &As[buf][(size_t)(tid+512)*8]); \
        gload_lds16(bS0 + (k0), &Bs[buf][(size_t)tid*8]); \
    }while(0)

    // counted-lgkmcnt interleaved compute: read groups pinned with sched_barrier.
    #define COMPUTE(buf, tt) do{ \
        short8v af[4], bf[4]; \
        _Pragma("unroll") \
        for (int m = 0; m < 4; ++m) af[m] = *(const short8v*)((const char*)As[buf] + offA[m]); \
        bf[0] = *(const short8v*)((const char*)Bs[buf] + offB[0]); \
        SB(); \
        bf[1] = *(const short8v*)((const char*)Bs[buf] + offB[1]); \
        SB(); \
        bf[2] = *(const short8v*)((const char*)Bs[buf] + offB[2]); \
        SB(); \
        bf[3] = *(const short8v*)((const char*)Bs[buf] + offB[3]); \
        SB(); \
        asm volatile("s_waitcnt lgkmcnt(3)" ::: "memory"); \
        SB(); \
        _Pragma("unroll") \
        for (int m = 0; m < 4; ++m) acc[m][0] = __builtin_amdgcn_mfma_f32_16x16x32_bf16(af[m], bf[0], acc[m][0], 0, 0, 0); \
        asm volatile("s_waitcnt lgkmcnt(2)" ::: "memory"); \
        SB(); \
        _Pragma("unroll") \
        for (int m = 0; m < 4; ++m) acc[m][1] = __builtin_amdgcn_mfma_f32_16x16x32_bf16(af[m], bf[1], acc[m][1], 0, 0, 0); \
        asm volatile("s_waitcnt lgkmcnt(1)" ::: "memory"); \
        SB(); \
        _Pragma("unroll") \
        for (int m = 0; m < 4; ++m) acc[m][2] = __builtin_amdgcn_mfma_f32_16x16x32_bf16(af[m], bf[2], acc[m][2], 0, 0, 0); \
        asm volatile("s_waitcnt lgkmcnt(0)" ::: "memory"); \
        SB(); \
        __builtin_amdgcn_s_barrier(); \
        if ((tt) + 2 < NT) STAGE(buf, (size_t)((tt)+2)*32); \
        _Pragma("unroll") \
        for (int m = 0; m < 4; ++m) acc[m][3] = __builtin_amdgcn_mfma_f32_16x16x32_bf16(af[m], bf[3], acc[m][3], 0, 0, 0); \
    }while(0)

    int NT = K >> 5;
    STAGE(0, 0);
    STAGE(1, 32);
    int t = 0;
    for (; t < NT-1; ++t){
        vmw(3);
        SB();
        __builtin_amdgcn_s_barrier();
        COMPUTE(t & 1, t);
    }
    {
        vmw(0);
        SB();
        __builtin_amdgcn_s_barrier();
        COMPUTE(t & 1, t);
    }
    #undef COMPUTE
    #undef STAGE

    int rrow = (lane >> 4) * 4;
    int rcol = lane & 15;
    unsigned short* outp;
    int colbase;
    if (n0 < 2048){ outp = Cout0; colbase = n0; }
    else          { outp = Cout1; colbase = n0 - 2048; }
    #pragma unroll
    for (int m = 0; m < 4; ++m)
        #pragma unroll
        for (int n = 0; n < 4; ++n){
            int cc = colbase + wcol*64 + n*16 + rcol;
            #pragma unroll
            for (int i = 0; i < 4; ++i){
                int rr = m0 + wrow*64 + m*16 + rrow + i;
                outp[(size_t)rr*2048 + cc] = f2bf_bits(acc[m][n][i]);
            }
        }
}

// ---------------- K=2048 GEMM: 512 threads, 128x128 tile, DEPTH 4 ----------------
template<int MODE, int MAP>
__global__ __launch_bounds__(512) void gemm_k2048(const unsigned short* __restrict__ A,
                                                  const unsigned short* __restrict__ W,
                                                  void* __restrict__ Cout0,
                                                  const float* __restrict__ resid,
                                                  int M, int N, int K){
    __shared__ unsigned short As[4][128*32];
    __shared__ unsigned short Bs[4][128*32];
    int tid = threadIdx.x;
    int bid = blockIdx.x;
    int m0, n0;
    if (MAP == 0){
        int x = bid & 7, sw = bid >> 3;
        int ml = sw >> 2, nl = sw & 3;
        m0 = ((x & 3)*8 + ml) * 128;
        n0 = (((x >> 2)*4) + nl) * 128;
    } else {
        int x = bid & 7, sw = bid >> 3;
        m0 = (x*4 + sw/9) * 128;
        n0 = (sw % 9) * 128;
    }

    int lane = tid & 63;
    int w = tid >> 6;
    int wrow = w >> 2, wcol = w & 3;
    f32x4 acc[4][2];
    #pragma unroll
    for (int i = 0; i < 4; ++i)
        #pragma unroll
        for (int j = 0; j < 2; ++j) acc[i][j] = (f32x4){0.f,0.f,0.f,0.f};

    int g0 = tid >> 3, s0 = tid & 7;
    int swz0 = (s0*16) ^ ((g0&7)<<4);
    int r0 = 2*g0 + (swz0 >> 6);
    int c0e = (swz0 & 63) >> 1;
    const unsigned short* aS = A + (size_t)(m0 + r0)*K + c0e;
    const unsigned short* bS = W + (size_t)(n0 + r0)*K + c0e;

    int frow = lane & 15;
    int fkb  = (lane >> 4) * 16;
    int offA[4], offB[2];
    #pragma unroll
    for (int m = 0; m < 4; ++m){
        int r = wrow*64 + m*16 + frow;
        int lb = (r&1)*64 + fkb;
        offA[m] = (r>>1)*128 + (lb ^ (((r>>1)&7)<<4));
    }
    #pragma unroll
    for (int n = 0; n < 2; ++n){
        int r = wcol*32 + n*16 + frow;
        int lb = (r&1)*64 + fkb;
        offB[n] = (r>>1)*128 + (lb ^ (((r>>1)&7)<<4));
    }

    #define STAGE(buf, k0) do{ \
        gload_lds16(aS + (k0), &As[buf][(size_t)tid*8]); \
        gload_lds16(bS + (k0), &Bs[buf][(size_t)tid*8]); \
    }while(0)

    #define COMPUTE(buf, tt) do{ \
        short8v af[4], bf[2]; \
        _Pragma("unroll") \
        for (int m = 0; m < 4; ++m) af[m] = *(const short8v*)((const char*)As[buf] + offA[m]); \
        bf[0] = *(const short8v*)((const char*)Bs[buf] + offB[0]); \
        SB(); \
        bf[1] = *(const short8v*)((const char*)Bs[buf] + offB[1]); \
        SB(); \
        asm volatile("s_waitcnt lgkmcnt(1)" ::: "memory"); \
        SB(); \
        _Pragma("unroll") \
        for (int m = 0; m < 4; ++m) acc[m][0] = __builtin_amdgcn_mfma_f32_16x16x32_bf16(af[m], bf[0], acc[m][0], 0, 0, 0); \
        asm volatile("s_waitcnt lgkmcnt(0)" ::: "memory"); \
        SB(); \
        __builtin_amdgcn_s_barrier(); \
        if ((tt) + 4 < NT) STAGE(buf, (size_t)((tt)+4)*32); \
        _Pragma("unroll") \
        for (int m = 0; m < 4; ++m) acc[m][1] = __builtin_amdgcn_mfma_f32_16x16x32_bf16(af[m], bf[1], acc[m][1], 0, 0, 0); \
    }while(0)

    int NT = K >> 5;
    #pragma unroll
    for (int p = 0; p < 4; ++p) STAGE(p, (size_t)p*32);

    int t = 0;
    for (; t < NT-3; ++t){
        vmw(6);
        SB();
        __builtin_amdgcn_s_barrier();
        COMPUTE(t & 3, t);
    }
    #pragma unroll
    for (int j = 2; j >= 0; --j){
        vmw(2*j);
        SB();
        __builtin_amdgcn_s_barrier();
        COMPUTE(t & 3, t);
        ++t;
    }
    #undef COMPUTE
    #undef STAGE

    int rrow = (lane >> 4) * 4;
    int rcol = lane & 15;
    if (MODE == 2){
        float* Co = (float*)Cout0;
        #pragma unroll
        for (int m = 0; m < 4; ++m)
            #pragma unroll
            for (int n = 0; n < 2; ++n){
                int cc = n0 + wcol*32 + n*16 + rcol;
                #pragma unroll
                for (int i = 0; i < 4; ++i){
                    int rr = m0 + wrow*64 + m*16 + rrow + i;
                    Co[(size_t)rr*N + cc] = acc[m][n][i] + resid[(size_t)rr*N + cc];
                }
            }
    } else {
        unsigned short* outp = (unsigned short*)Cout0;
        #pragma unroll
        for (int m = 0; m < 4; ++m)
            #pragma unroll
            for (int n = 0; n < 2; ++n){
                int cc = n0 + wcol*32 + n*16 + rcol;
                #pragma unroll
                for (int i = 0; i < 4; ++i){
                    int rr = m0 + wrow*64 + m*16 + rrow + i;
                    outp[(size_t)rr*N + cc] = f2bf_bits(acc[m][n][i]);
                }
            }
    }
}

// ---------------- conv(K=4)+SiLU: 8 rows per block, rolling register window ----------------
__global__ __launch_bounds__(256) void conv_silu_kernel(const unsigned short* __restrict__ xp,
                                                        const float* __restrict__ cw,
                                                        const float* __restrict__ cb,
                                                        unsigned short* __restrict__ xs){
    int bid = blockIdx.x;                          // 512 blocks
    int r0 = ((bid & 7)*64 + (bid >> 3)) * 8;
    int t0 = r0 & (SEQ - 1);
    int tid = threadIdx.x;
    int c8 = tid*8;

    float4 cwv[8];
    #pragma unroll
    for (int k = 0; k < 8; ++k) cwv[k] = ((const float4*)cw)[c8 + k];
    float cbv[8];
    {
        float4 cb0 = ((const float4*)cb)[tid*2];
        float4 cb1 = ((const float4*)cb)[tid*2+1];
        cbv[0]=cb0.x; cbv[1]=cb0.y; cbv[2]=cb0.z; cbv[3]=cb0.w;
        cbv[4]=cb1.x; cbv[5]=cb1.y; cbv[6]=cb1.z; cbv[7]=cb1.w;
    }

    ushort8v zero8 = {0,0,0,0,0,0,0,0};
    ushort8v xm3, xm2, xm1, cur, nxt;
    if (t0 >= 3){
        xm3 = *(const ushort8v*)(xp + (size_t)(r0-3)*D_INNER + c8);
        xm2 = *(const ushort8v*)(xp + (size_t)(r0-2)*D_INNER + c8);
        xm1 = *(const ushort8v*)(xp + (size_t)(r0-1)*D_INNER + c8);
    } else {
        xm3 = zero8; xm2 = zero8; xm1 = zero8;
    }
    cur = *(const ushort8v*)(xp + (size_t)r0*D_INNER + c8);

    #pragma unroll
    for (int i = 0; i < 8; ++i){
        if (i < 7) nxt = *(const ushort8v*)(xp + (size_t)(r0+i+1)*D_INNER + c8);
        ushort8v o;
        #pragma unroll
        for (int k = 0; k < 8; ++k){
            float a = cbv[k]
                    + bf2f(xm3[k])*cwv[k].x
                    + bf2f(xm2[k])*cwv[k].y
                    + bf2f(xm1[k])*cwv[k].z
                    + bf2f(cur[k])*cwv[k].w;
            o[k] = f2bf_bits(silu_f(a));
        }
        *(ushort8v*)(xs + (size_t)(r0+i)*D_INNER + c8) = o;
        xm3 = xm2; xm2 = xm1; xm1 = cur; cur = nxt;
    }
}

// ---------------- xdT: full head per block (4 d-subtiles), cached dt, emits cums ----------------
__global__ __launch_bounds__(256) void xdT_kernel(const unsigned short* __restrict__ xs,
                                                  const unsigned short* __restrict__ BCm,
                                                  const float* __restrict__ dt_b,
                                                  const float* __restrict__ A_log,
                                                  unsigned short* __restrict__ xdT,
                                                  float* __restrict__ cums){
    int ct = blockIdx.x, bh = blockIdx.y;
    int b = bh >> 3, h = bh & 7;
    __shared__ unsigned short sT[64*68];
    __shared__ float sdt[64];
    int tid = threadIdx.x;
    if (tid < 64){
        int t = ct*64 + tid;
        float raw = bf2f(BCm[(size_t)(b*SEQ + t)*BCN + 1024 + h]);
        float dtv = softplus_f(raw + dt_b[h]);
        sdt[tid] = dtv;
        float Ah = -__expf(A_log[h]);
        float a = dtv * Ah;
        #pragma unroll
        for (int i = 1; i < 64; i <<= 1){
            float v = __shfl_up(a, i);
            if (tid >= i) a += v;
        }
        cums[((size_t)bh)*SEQ + t] = a;
    }
    __syncthreads();
    for (int cd = 0; cd < 4; ++cd){
        #pragma unroll
        for (int it = 0; it < 2; ++it){
            int l = tid + it*256;
            int tl = l >> 3, seg = l & 7;
            int row = b*SEQ + ct*64 + tl;
            ushort8v v = *(const ushort8v*)(xs + (size_t)row*D_INNER + h*D_HEAD + cd*64 + seg*8);
            float dtv = sdt[tl];
            ushort4v lo, hi;
            #pragma unroll
            for (int j = 0; j < 4; ++j){
                lo[j] = f2bf_bits(bf2f(v[j]) * dtv);
                hi[j] = f2bf_bits(bf2f(v[j+4]) * dtv);
            }
            *(ushort4v*)((char*)sT + tl*136 + seg*16)     = lo;
            *(ushort4v*)((char*)sT + tl*136 + seg*16 + 8) = hi;
        }
        __syncthreads();
        #pragma unroll
        for (int it = 0; it < 2; ++it){
            int l = tid + it*256;
            int dl = l >> 3, tseg = l & 7;
            ushort8v o;
            #pragma unroll
            for (int j = 0; j < 8; ++j) o[j] = sT[(tseg*8 + j)*68 + dl];
            *(ushort8v*)(xdT + ((size_t)bh*D_HEAD + cd*64 + dl)*SEQ + ct*64 + tseg*8) = o;
        }
        __syncthreads();
    }
}

// ---------------- chunk_state (MFMA), d-split ----------------
__global__ __launch_bounds__(256) void chunk_state_mfma(const unsigned short* __restrict__ xdT,
                                                        const unsigned short* __restrict__ BCm,
                                                        const float* __restrict__ cums,
                                                        unsigned short* __restrict__ HSb){
    int c = blockIdx.x;
    int by = blockIdx.y;
    int h = by >> 1, dh = by & 1;
    int b = blockIdx.z;
    int tid = threadIdx.x;
    int bh = b*N_HEADS + h;
    int t0 = c*64;
    __shared__ unsigned short sX[128*64];
    __shared__ unsigned short sBdT[64*72];
    __shared__ float sdec[64];
    if (tid < 64)
        sdec[tid] = __expf(cums[(size_t)bh*SEQ + t0 + 63] - cums[(size_t)bh*SEQ + t0 + tid]);
    const unsigned short* xb = xdT + ((size_t)bh*D_HEAD + dh*128)*SEQ + t0;
    #pragma unroll
    for (int it = 0; it < 4; ++it){
        int l = tid + it*256;
        int d = l >> 3, seg = l & 7;
        gload_lds16(xb + (size_t)d*SEQ + (((seg*16) ^ ((d&7)<<4)) >> 1),
                    (char*)sX + (size_t)l*16);
    }
    __syncthreads();
    #pragma unroll
    for (int it = 0; it < 2; ++it){
        int l = tid + it*256;
        int tl = l >> 3, seg = l & 7;
        ushort8v bv = *(const ushort8v*)(BCm + (size_t)(b*SEQ + t0 + tl)*BCN + h*64 + seg*8);
        float dec = sdec[tl];
        #pragma unroll
        for (int j = 0; j < 8; ++j)
            sBdT[(seg*8 + j)*72 + tl] = f2bf_bits(bf2f(bv[j]) * dec);
    }
    __syncthreads();

    int lane = tid & 63, w = tid >> 6;
    int d0 = w*32;
    int fr = lane & 15, fk = (lane >> 4)*8;
    f32x4 acc[2][4];
    #pragma unroll
    for (int i = 0; i < 2; ++i)
        #pragma unroll
        for (int j = 0; j < 4; ++j) acc[i][j] = (f32x4){0.f,0.f,0.f,0.f};
    short8v af[2][2], bg[4][2];
    #pragma unroll
    for (int m = 0; m < 2; ++m)
        #pragma unroll
        for (int k = 0; k < 2; ++k){
            int d = d0 + m*16 + fr;
            af[m][k] = *(const short8v*)((const char*)sX + (size_t)d*128 + (((k*32+fk)*2) ^ ((d&7)<<4)));
        }
    #pragma unroll
    for (int n = 0; n < 4; ++n)
        #pragma unroll
        for (int k = 0; k < 2; ++k)
            bg[n][k] = *(const short8v*)(sBdT + (size_t)(n*16 + fr)*72 + k*32 + fk);
    #pragma unroll
    for (int k = 0; k < 2; ++k)
        #pragma unroll
        for (int m = 0; m < 2; ++m)
            #pragma unroll
            for (int n = 0; n < 4; ++n)
                acc[m][n] = __builtin_amdgcn_mfma_f32_16x16x32_bf16(af[m][k], bg[n][k], acc[m][n], 0, 0, 0);

    unsigned short* out = HSb + ((size_t)bh*NCHUNK + c)*16384 + (size_t)dh*128*64;
    int rr = (lane >> 4)*4, rc = lane & 15;
    #pragma unroll
    for (int m = 0; m < 2; ++m)
        #pragma unroll
        for (int n = 0; n < 4; ++n)
            #pragma unroll
            for (int i = 0; i < 4; ++i)
                out[(size_t)(d0 + m*16 + rr + i)*64 + n*16 + rc] = f2bf_bits(acc[m][n][i]);
}

// ---------------- chunk recurrence over bf16 states ----------------
__global__ __launch_bounds__(256) void state_pass_kernel(const float* __restrict__ cums,
                                                         unsigned short* __restrict__ HSb){
    int e2 = blockIdx.x*256 + threadIdx.x;
    int bh = blockIdx.y;
    float Hx = 0.f, Hy = 0.f;
    ushort2v* p = (ushort2v*)(HSb + (size_t)bh*NCHUNK*16384) + e2;
    const float* cp = cums + (size_t)bh*SEQ + 63;
    for (int c = 0; c < NCHUNK; ++c){
        float Pc = __expf(cp[(size_t)c*64]);
        ushort2v s = *p;
        float sx = bf2f(s[0]), sy = bf2f(s[1]);
        ushort2v hold;
        hold[0] = f2bf_bits(Hx); hold[1] = f2bf_bits(Hy);
        *p = hold;
        Hx = fmaf(Pc, Hx, sx);
        Hy = fmaf(Pc, Hy, sy);
        p += 8192;
    }
}

// ---------------- chunk_out (MFMA), d-split ----------------
__global__ __launch_bounds__(256) void chunk_out_mfma(const unsigned short* __restrict__ xs,
                                                      const unsigned short* __restrict__ z,
                                                      const unsigned short* __restrict__ BCm,
                                                      const unsigned short* __restrict__ xdT,
                                                      const float* __restrict__ cums,
                                                      const unsigned short* __restrict__ HSb,
                                                      const float* __restrict__ Dp,
                                                      unsigned short* __restrict__ y){
    int c = blockIdx.x;
    int by = blockIdx.y;
    int h = by >> 1, dh = by & 1;
    int b = blockIdx.z;
    int tid = threadIdx.x;
    int bh = b*N_HEADS + h;
    int t0 = c*64;
    __shared__ unsigned short regA[128*64];
    __shared__ unsigned short sW[64*64];
    __shared__ unsigned short sCd[64*64];
    __shared__ float scum[64];
    unsigned short* Craw = regA;
    unsigned short* Braw = regA + 64*64;

    if (tid < 64) scum[tid] = cums[(size_t)bh*SEQ + t0 + tid];
    #pragma unroll
    for (int it = 0; it < 2; ++it){
        int l = tid + it*256;
        int tl = l >> 3, seg = l & 7;
        size_t rowoff = (size_t)(b*SEQ + t0 + tl)*BCN + h*64;
        int soff = ((seg*16) ^ ((tl&7)<<4)) >> 1;
        gload_lds16(BCm + rowoff + 512 + soff, (char*)Craw + (size_t)l*16);
        gload_lds16(BCm + rowoff + soff,       (char*)Braw + (size_t)l*16);
    }
    __syncthreads();

    int lane = tid & 63, w = tid >> 6;
    int fr = lane & 15, fk = (lane >> 4)*8;
    int rr = (lane >> 4)*4, rc = lane & 15;

    int wr = w >> 1, wc = w & 1;
    f32x4 g[2][2];
    #pragma unroll
    for (int i = 0; i < 2; ++i)
        #pragma unroll
        for (int j = 0; j < 2; ++j) g[i][j] = (f32x4){0.f,0.f,0.f,0.f};
    {
        short8v ca[2][2], bb[2][2];
        #pragma unroll
        for (int m = 0; m < 2; ++m)
            #pragma unroll
            for (int k = 0; k < 2; ++k){
                int t = wr*32 + m*16 + fr;
                ca[m][k] = *(const short8v*)((const char*)Craw + (size_t)t*128 + (((k*32+fk)*2) ^ ((t&7)<<4)));
            }
        #pragma unroll
        for (int n = 0; n < 2; ++n)
            #pragma unroll
            for (int k = 0; k < 2; ++k){
                int s = wc*32 + n*16 + fr;
                bb[n][k] = *(const short8v*)((const char*)Braw + (size_t)s*128 + (((k*32+fk)*2) ^ ((s&7)<<4)));
            }
        #pragma unroll
        for (int k = 0; k < 2; ++k)
            #pragma unroll
            for (int m = 0; m < 2; ++m)
                #pragma unroll
                for (int n = 0; n < 2; ++n)
                    g[m][n] = __builtin_amdgcn_mfma_f32_16x16x32_bf16(ca[m][k], bb[n][k], g[m][n], 0, 0, 0);
    }
    #pragma unroll
    for (int m = 0; m < 2; ++m)
        #pragma unroll
        for (int n = 0; n < 2; ++n)
            #pragma unroll
            for (int i = 0; i < 4; ++i){
                int t = wr*32 + m*16 + rr + i;
                int s = wc*32 + n*16 + rc;
                float wv = (s <= t) ? __expf(scum[t] - scum[s]) * g[m][n][i] : 0.f;
                *(unsigned short*)((char*)sW + (size_t)t*128 + ((s*2) ^ ((t&7)<<4))) = f2bf_bits(wv);
            }
    {
        int tl = tid >> 2, sg = tid & 3;
        float ef = __expf(scum[tl]);
        #pragma unroll
        for (int q = 0; q < 2; ++q){
            int off = ((sg*32 + q*16)) ^ ((tl&7)<<4);
            ushort8v cv = *(const ushort8v*)((const char*)Craw + (size_t)tl*128 + off);
            ushort8v ov;
            #pragma unroll
            for (int j = 0; j < 8; ++j) ov[j] = f2bf_bits(bf2f(cv[j]) * ef);
            *(ushort8v*)((char*)sCd + (size_t)tl*128 + off) = ov;
        }
    }
    __syncthreads();

    const unsigned short* xb = xdT + ((size_t)bh*D_HEAD + dh*128)*SEQ + t0;
    #pragma unroll
    for (int it = 0; it < 4; ++it){
        int l = tid + it*256;
        int d = l >> 3, seg = l & 7;
        gload_lds16(xb + (size_t)d*SEQ + (((seg*16) ^ ((d&7)<<4)) >> 1),
                    (char*)regA + (size_t)l*16);
    }
    __syncthreads();

    int d0 = w*32;
    f32x4 acc[4][2];
    #pragma unroll
    for (int i = 0; i < 4; ++i)
        #pragma unroll
        for (int j = 0; j < 2; ++j) acc[i][j] = (f32x4){0.f,0.f,0.f,0.f};
    {
        short8v aw[4][2], xd[2][2];
        #pragma unroll
        for (int m = 0; m < 4; ++m)
            #pragma unroll
            for (int k = 0; k < 2; ++k){
                int t = m*16 + fr;
                aw[m][k] = *(const short8v*)((const char*)sW + (size_t)t*128 + (((k*32+fk)*2) ^ ((t&7)<<4)));
            }
        #pragma unroll
        for (int n = 0; n < 2; ++n)
            #pragma unroll
            for (int k = 0; k < 2; ++k){
                int d = d0 + n*16 + fr;
                xd[n][k] = *(const short8v*)((const char*)regA + (size_t)d*128 + (((k*32+fk)*2) ^ ((d&7)<<4)));
            }
        #pragma unroll
        for (int k = 0; k < 2; ++k)
            #pragma unroll
            for (int m = 0; m < 4; ++m)
                #pragma unroll
                for (int n = 0; n < 2; ++n)
                    acc[m][n] = __builtin_amdgcn_mfma_f32_16x16x32_bf16(aw[m][k], xd[n][k], acc[m][n], 0, 0, 0);
    }
    __syncthreads();

    const unsigned short* hb = HSb + ((size_t)bh*NCHUNK + c)*16384 + (size_t)dh*128*64;
    #pragma unroll
    for (int it = 0; it < 4; ++it){
        int l = tid + it*256;
        int d = l >> 3, seg = l & 7;
        gload_lds16(hb + (size_t)d*64 + (((seg*16) ^ ((d&7)<<4)) >> 1),
                    (char*)regA + (size_t)l*16);
    }
    __syncthreads();

    {
        short8v aw[4][2], ht[2][2];
        #pragma unroll
        for (int m = 0; m < 4; ++m)
            #pragma unroll
            for (int k = 0; k < 2; ++k){
                int t = m*16 + fr;
                aw[m][k] = *(const short8v*)((const char*)sCd + (size_t)t*128 + (((k*32+fk)*2) ^ ((t&7)<<4)));
            }
        #pragma unroll
        for (int n = 0; n < 2; ++n)
            #pragma unroll
            for (int k = 0; k < 2; ++k){
                int d = d0 + n*16 + fr;
                ht[n][k] = *(const short8v*)((const char*)regA + (size_t)d*128 + (((k*32+fk)*2) ^ ((d&7)<<4)));
            }
        #pragma unroll
        for (int k = 0; k < 2; ++k)
            #pragma unroll
            for (int m = 0; m < 4; ++m)
                #pragma unroll
                for (int n = 0; n < 2; ++n)
                    acc[m][n] = __builtin_amdgcn_mfma_f32_16x16x32_bf16(aw[m][k], ht[n][k], acc[m][n], 0, 0, 0);
    }

    float Dh = Dp[h];
    #pragma unroll
    for (int m = 0; m < 4; ++m)
        #pragma unroll
        for (int n = 0; n < 2; ++n)
            #pragma unroll
            for (int i = 0; i < 4; ++i){
                int t = m*16 + rr + i;
                int d = dh*128 + d0 + n*16 + rc;
                size_t off = (size_t)(b*SEQ + t0 + t)*D_INNER + h*D_HEAD + d;
                float val = acc[m][n][i] + Dh * bf2f(xs[off]);
                y[off] = f2bf_bits(val * silu_f(bf2f(z[off])));
            }
}

// ---------------- launch ----------------
extern "C" void kernel_launch(void* const* d_in, const int* in_sizes, int n_in,
                              void* d_out, int out_size, void* d_ws, size_t ws_size,
                              hipStream_t stream){
    const float* x      = (const float*)d_in[0];
    const float* norm_w = (const float*)d_in[1];
    const float* in_w   = (const float*)d_in[2];
    const float* conv_w = (const float*)d_in[3];
    const float* conv_b = (const float*)d_in[4];
    const float* A_log  = (const float*)d_in[5];
    const float* B_w    = (const float*)d_in[6];
    const float* C_w    = (const float*)d_in[7];
    const float* dt_w   = (const float*)d_in[8];
    const float* dt_b   = (const float*)d_in[9];
    const float* Dp     = (const float*)d_in[10];
    const float* out_w  = (const float*)d_in[11];
    float* out = (float*)d_out;

    char* ws = (char*)d_ws;
    const size_t MB = 1048576ull;
    unsigned short* xpre_bf = (unsigned short*)(ws);             // [0,16) ; reused as y
    unsigned short* y_bf    = xpre_bf;
    unsigned short* z_bf    = (unsigned short*)(ws + 16*MB);     // [16,32)
    unsigned short* xs_bf   = (unsigned short*)(ws + 32*MB);     // [32,48)
    unsigned short* inw_bf  = (unsigned short*)(ws + 48*MB);     // [48,56) dead before xdT written
    unsigned short* xdT     = (unsigned short*)(ws + 48*MB);     // [48,64)
    unsigned short* HSb     = (unsigned short*)(ws + 64*MB);     // [64,80)
    unsigned short* BCm     = (unsigned short*)(ws + 80*MB);     // [80,89.1)
    unsigned short* outw_bf = (unsigned short*)(ws + 90*MB);     // [90,94)
    unsigned short* xn_bf   = (unsigned short*)(ws + 94*MB);     // [94,102)
    unsigned short* BCw_bf  = (unsigned short*)(ws + 102*MB);    // [102,106.5)
    float*          cums    = (float*)(ws + 107*MB);             // 128 KB

    prep_kernel<<<12544, 256, 0, stream>>>(in_w, out_w, B_w, C_w, dt_w, x, norm_w,
                                           inw_bf, outw_bf, BCw_bf, xn_bf);

    gemm_in512<<<512, 512, 0, stream>>>(xn_bf, inw_bf, xpre_bf, z_bf);

    conv_silu_kernel<<<512, 256, 0, stream>>>(xpre_bf, conv_w, conv_b, xs_bf);

    gemm_k2048<0,1><<<288, 512, 0, stream>>>(xs_bf, BCw_bf, BCm, nullptr,
        ROWS, BCN, D_INNER);

    xdT_kernel<<<dim3(SEQ/64, BATCH*N_HEADS), 256, 0, stream>>>(xs_bf, BCm, dt_b, A_log, xdT, cums);

    chunk_state_mfma<<<dim3(NCHUNK, N_HEADS*2, BATCH), 256, 0, stream>>>(xdT, BCm, cums, HSb);

    state_pass_kernel<<<dim3(32, BATCH*N_HEADS), 256, 0, stream>>>(cums, HSb);

    chunk_out_mfma<<<dim3(NCHUNK, N_HEADS*2, BATCH), 256, 0, stream>>>(xs_bf, z_bf, BCm, xdT, cums, HSb, Dp, y_bf);

    gemm_k2048<2,0><<<256, 512, 0, stream>>>(y_bf, outw_bf, out, x,
        ROWS, D_MODEL, D_INNER);
}

// Round 21
// 169.703 us; speedup vs baseline: 1.0020x; 1.0020x over previous
//
#include <hip/hip_runtime.h>
#include <hip/hip_bf16.h>
#include <math.h>

#define D_MODEL 1024
#define D_STATE 64
#define D_CONV  4
#define D_INNER 2048
#define N_HEADS 8
#define D_HEAD  256
#define BATCH   2
#define SEQ     2048
#define ROWS    (BATCH*SEQ)   /* 4096 */
#define NCHUNK  32            /* SEQ/64 */
#define BCN     1152          /* BC gemm N: 512 B + 512 C + 8 dt + 120 pad */
#define EPS     1e-6f

typedef __attribute__((ext_vector_type(2))) unsigned short ushort2v;
typedef __attribute__((ext_vector_type(4))) unsigned short ushort4v;
typedef __attribute__((ext_vector_type(8))) unsigned short ushort8v;
typedef __attribute__((ext_vector_type(8))) short short8v;
typedef __attribute__((ext_vector_type(4))) float f32x4;

__device__ __forceinline__ float silu_f(float x){ return x / (1.0f + __expf(-x)); }
__device__ __forceinline__ float softplus_f(float x){ return (x > 20.0f) ? x : log1pf(__expf(x)); }
__device__ __forceinline__ float bf2f(unsigned short u){
    union { unsigned int i; float f; } v; v.i = ((unsigned int)u) << 16; return v.f;
}
__device__ __forceinline__ unsigned short f2bf_bits(float f){
    __hip_bfloat16 h = __float2bfloat16(f);
    return *(unsigned short*)&h;
}
__device__ __forceinline__ void gload_lds16(const void* g, void* l){
    __builtin_amdgcn_global_load_lds((const __attribute__((address_space(1))) void*)g,
                                     (__attribute__((address_space(3))) void*)l, 16, 0, 0);
}
__device__ __forceinline__ void vmw(int n){
    switch(n){
        case 0:  asm volatile("s_waitcnt vmcnt(0)"  ::: "memory"); break;
        case 2:  asm volatile("s_waitcnt vmcnt(2)"  ::: "memory"); break;
        case 3:  asm volatile("s_waitcnt vmcnt(3)"  ::: "memory"); break;
        case 4:  asm volatile("s_waitcnt vmcnt(4)"  ::: "memory"); break;
        case 6:  asm volatile("s_waitcnt vmcnt(6)"  ::: "memory"); break;
        default: asm volatile("s_waitcnt vmcnt(0)"  ::: "memory"); break;
    }
}

// ---------------- prep: weight conversions + BC/dt assembly + rmsnorm (fused) ----------------
__global__ __launch_bounds__(256) void prep_kernel(const float* __restrict__ in_w,
                                                   const float* __restrict__ out_w,
                                                   const float* __restrict__ B_w,
                                                   const float* __restrict__ C_w,
                                                   const float* __restrict__ dt_w,
                                                   const float* __restrict__ x,
                                                   const float* __restrict__ norm_w,
                                                   unsigned short* __restrict__ inw_bf,
                                                   unsigned short* __restrict__ outw_bf,
                                                   unsigned short* __restrict__ BCw_bf,
                                                   unsigned short* __restrict__ xn){
    __shared__ float red[4];
    int bid = blockIdx.x;
    int tid = threadIdx.x;
    if (bid >= 8448){
        int row = bid - 8448;
        const float4* xr = (const float4*)(x + (size_t)row * D_MODEL);
        float4 a = xr[tid];
        float ss = a.x*a.x + a.y*a.y + a.z*a.z + a.w*a.w;
        #pragma unroll
        for (int i = 1; i < 64; i <<= 1) ss += __shfl_xor(ss, i);
        int lane = tid & 63, wid = tid >> 6;
        if (lane == 0) red[wid] = ss;
        __syncthreads();
        float tot = red[0] + red[1] + red[2] + red[3];
        float scale = rsqrtf(tot * (1.0f / D_MODEL) + EPS);
        float4 wv = ((const float4*)norm_w)[tid];
        ushort4v o;
        o[0] = f2bf_bits(a.x * scale * wv.x);
        o[1] = f2bf_bits(a.y * scale * wv.y);
        o[2] = f2bf_bits(a.z * scale * wv.z);
        o[3] = f2bf_bits(a.w * scale * wv.w);
        ((ushort4v*)(xn + (size_t)row * D_MODEL))[tid] = o;
        return;
    }
    int i = bid * 256 + tid;
    const float* src; unsigned short* dst; int j;
    if (i < 1048576)      { src = in_w;  dst = inw_bf;            j = i; }
    else if (i < 1572864) { src = out_w; dst = outw_bf;           j = i - 1048576; }
    else if (i < 1835008) { src = B_w;   dst = BCw_bf;            j = i - 1572864; }
    else if (i < 2097152) { src = C_w;   dst = BCw_bf + 1048576;  j = i - 1835008; }
    else {
        int k = i - 2097152;
        int drow = k >> 9;
        int col4 = k & 511;
        ushort4v o = {0,0,0,0};
        if (drow < 8){
            float4 v = ((const float4*)(dt_w + (size_t)drow*D_INNER))[col4];
            o[0] = f2bf_bits(v.x); o[1] = f2bf_bits(v.y);
            o[2] = f2bf_bits(v.z); o[3] = f2bf_bits(v.w);
        }
        ((ushort4v*)(BCw_bf + (size_t)(1024 + drow)*D_INNER))[col4] = o;
        return;
    }
    float4 v = ((const float4*)src)[j];
    ushort4v o;
    o[0] = f2bf_bits(v.x); o[1] = f2bf_bits(v.y);
    o[2] = f2bf_bits(v.z); o[3] = f2bf_bits(v.w);
    ((ushort4v*)dst)[j] = o;
}

// ---------------- in_proj GEMM: 512 threads, 256x128 tile, counted-vmcnt 2-deep ----------------
__global__ __launch_bounds__(512) void gemm_in512(const unsigned short* __restrict__ A,
                                                  const unsigned short* __restrict__ W,
                                                  unsigned short* __restrict__ Cout0,
                                                  unsigned short* __restrict__ Cout1){
    const int K = D_MODEL;
    __shared__ unsigned short As[2][256*32];
    __shared__ unsigned short Bs[2][128*32];
    int tid = threadIdx.x;
    int bid = blockIdx.x;
    int x = bid & 7;
    int r = bid >> 3;
    int m0 = ((x & 3)*4 + (r >> 4)) * 256;
    int n0 = ((x >> 2)*16 + (r & 15)) * 128;

    int lane = tid & 63;
    int w = tid >> 6;
    int wrow = w >> 1, wcol = w & 1;
    f32x4 acc[4][4];
    #pragma unroll
    for (int i = 0; i < 4; ++i)
        #pragma unroll
        for (int j = 0; j < 4; ++j) acc[i][j] = (f32x4){0.f,0.f,0.f,0.f};

    int g0 = tid >> 3, s0 = tid & 7;
    int swz0 = (s0*16) ^ ((g0&7)<<4);
    int r0 = 2*g0 + (swz0 >> 6);
    int c0e = (swz0 & 63) >> 1;
    const unsigned short* aS0 = A + (size_t)(m0 + r0)*K + c0e;
    const unsigned short* aS1 = aS0 + (size_t)128*K;
    const unsigned short* bS0 = W + (size_t)(n0 + r0)*K + c0e;

    int frow = lane & 15;
    int fkb  = (lane >> 4) * 16;
    int offA[4], offB[4];
    #pragma unroll
    for (int m = 0; m < 4; ++m){
        int rr = wrow*64 + m*16 + frow;
        int lb = (rr&1)*64 + fkb;
        offA[m] = (rr>>1)*128 + (lb ^ (((rr>>1)&7)<<4));
    }
    #pragma unroll
    for (int n = 0; n < 4; ++n){
        int rr = wcol*64 + n*16 + frow;
        int lb = (rr&1)*64 + fkb;
        offB[n] = (rr>>1)*128 + (lb ^ (((rr>>1)&7)<<4));
    }

    #define STAGE(buf, k0) do{ \
        gload_lds16(aS0 + (k0), &As[buf][(size_t)tid*8]); \
        gload_lds16(aS1 + (k0), &As[buf][(size_t)(tid+512)*8]); \
        gload_lds16(bS0 + (k0), &Bs[buf][(size_t)tid*8]); \
    }while(0)

    #define COMPUTE(buf, tt) do{ \
        short8v af[4], bf[4]; \
        _Pragma("unroll") \
        for (int m = 0; m < 4; ++m) af[m] = *(const short8v*)((const char*)As[buf] + offA[m]); \
        _Pragma("unroll") \
        for (int n = 0; n < 4; ++n) bf[n] = *(const short8v*)((const char*)Bs[buf] + offB[n]); \
        asm volatile("s_waitcnt lgkmcnt(0)" ::: "memory"); \
        __builtin_amdgcn_sched_barrier(0); \
        __builtin_amdgcn_s_barrier(); \
        if ((tt) + 2 < NT) STAGE(buf, (size_t)((tt)+2)*32); \
        _Pragma("unroll") \
        for (int m = 0; m < 4; ++m) \
            _Pragma("unroll") \
            for (int n = 0; n < 4; ++n) \
                acc[m][n] = __builtin_amdgcn_mfma_f32_16x16x32_bf16(af[m], bf[n], acc[m][n], 0, 0, 0); \
    }while(0)

    int NT = K >> 5;
    STAGE(0, 0);
    STAGE(1, 32);
    int t = 0;
    for (; t < NT-1; ++t){
        vmw(3);
        __builtin_amdgcn_sched_barrier(0);
        __builtin_amdgcn_s_barrier();
        COMPUTE(t & 1, t);
    }
    {
        vmw(0);
        __builtin_amdgcn_sched_barrier(0);
        __builtin_amdgcn_s_barrier();
        COMPUTE(t & 1, t);
    }
    #undef COMPUTE
    #undef STAGE

    int rrow = (lane >> 4) * 4;
    int rcol = lane & 15;
    unsigned short* outp;
    int colbase;
    if (n0 < 2048){ outp = Cout0; colbase = n0; }
    else          { outp = Cout1; colbase = n0 - 2048; }
    #pragma unroll
    for (int m = 0; m < 4; ++m)
        #pragma unroll
        for (int n = 0; n < 4; ++n){
            int cc = colbase + wcol*64 + n*16 + rcol;
            #pragma unroll
            for (int i = 0; i < 4; ++i){
                int rr = m0 + wrow*64 + m*16 + rrow + i;
                outp[(size_t)rr*2048 + cc] = f2bf_bits(acc[m][n][i]);
            }
        }
}

// ---------------- K=2048 GEMM: 512 threads, 128x128 tile, DEPTH 4 ----------------
template<int MODE, int MAP>
__global__ __launch_bounds__(512) void gemm_k2048(const unsigned short* __restrict__ A,
                                                  const unsigned short* __restrict__ W,
                                                  void* __restrict__ Cout0,
                                                  const float* __restrict__ resid,
                                                  int M, int N, int K){
    __shared__ unsigned short As[4][128*32];
    __shared__ unsigned short Bs[4][128*32];
    int tid = threadIdx.x;
    int bid = blockIdx.x;
    int m0, n0;
    if (MAP == 0){
        int x = bid & 7, sw = bid >> 3;
        int ml = sw >> 2, nl = sw & 3;
        m0 = ((x & 3)*8 + ml) * 128;
        n0 = (((x >> 2)*4) + nl) * 128;
    } else {
        int x = bid & 7, sw = bid >> 3;
        m0 = (x*4 + sw/9) * 128;
        n0 = (sw % 9) * 128;
    }

    int lane = tid & 63;
    int w = tid >> 6;
    int wrow = w >> 2, wcol = w & 3;
    f32x4 acc[4][2];
    #pragma unroll
    for (int i = 0; i < 4; ++i)
        #pragma unroll
        for (int j = 0; j < 2; ++j) acc[i][j] = (f32x4){0.f,0.f,0.f,0.f};

    int g0 = tid >> 3, s0 = tid & 7;
    int swz0 = (s0*16) ^ ((g0&7)<<4);
    int r0 = 2*g0 + (swz0 >> 6);
    int c0e = (swz0 & 63) >> 1;
    const unsigned short* aS = A + (size_t)(m0 + r0)*K + c0e;
    const unsigned short* bS = W + (size_t)(n0 + r0)*K + c0e;

    int frow = lane & 15;
    int fkb  = (lane >> 4) * 16;
    int offA[4], offB[2];
    #pragma unroll
    for (int m = 0; m < 4; ++m){
        int r = wrow*64 + m*16 + frow;
        int lb = (r&1)*64 + fkb;
        offA[m] = (r>>1)*128 + (lb ^ (((r>>1)&7)<<4));
    }
    #pragma unroll
    for (int n = 0; n < 2; ++n){
        int r = wcol*32 + n*16 + frow;
        int lb = (r&1)*64 + fkb;
        offB[n] = (r>>1)*128 + (lb ^ (((r>>1)&7)<<4));
    }

    #define STAGE(buf, k0) do{ \
        gload_lds16(aS + (k0), &As[buf][(size_t)tid*8]); \
        gload_lds16(bS + (k0), &Bs[buf][(size_t)tid*8]); \
    }while(0)

    #define COMPUTE(buf, tt) do{ \
        short8v af[4], bf[2]; \
        _Pragma("unroll") \
        for (int m = 0; m < 4; ++m) af[m] = *(const short8v*)((const char*)As[buf] + offA[m]); \
        _Pragma("unroll") \
        for (int n = 0; n < 2; ++n) bf[n] = *(const short8v*)((const char*)Bs[buf] + offB[n]); \
        asm volatile("s_waitcnt lgkmcnt(0)" ::: "memory"); \
        __builtin_amdgcn_sched_barrier(0); \
        __builtin_amdgcn_s_barrier(); \
        if ((tt) + 4 < NT) STAGE(buf, (size_t)((tt)+4)*32); \
        _Pragma("unroll") \
        for (int m = 0; m < 4; ++m) \
            _Pragma("unroll") \
            for (int n = 0; n < 2; ++n) \
                acc[m][n] = __builtin_amdgcn_mfma_f32_16x16x32_bf16(af[m], bf[n], acc[m][n], 0, 0, 0); \
    }while(0)

    int NT = K >> 5;
    #pragma unroll
    for (int p = 0; p < 4; ++p) STAGE(p, (size_t)p*32);

    int t = 0;
    for (; t < NT-3; ++t){
        vmw(6);
        __builtin_amdgcn_sched_barrier(0);
        __builtin_amdgcn_s_barrier();
        COMPUTE(t & 3, t);
    }
    #pragma unroll
    for (int j = 2; j >= 0; --j){
        vmw(2*j);
        __builtin_amdgcn_sched_barrier(0);
        __builtin_amdgcn_s_barrier();
        COMPUTE(t & 3, t);
        ++t;
    }
    #undef COMPUTE
    #undef STAGE

    int rrow = (lane >> 4) * 4;
    int rcol = lane & 15;
    if (MODE == 2){
        float* Co = (float*)Cout0;
        #pragma unroll
        for (int m = 0; m < 4; ++m)
            #pragma unroll
            for (int n = 0; n < 2; ++n){
                int cc = n0 + wcol*32 + n*16 + rcol;
                #pragma unroll
                for (int i = 0; i < 4; ++i){
                    int rr = m0 + wrow*64 + m*16 + rrow + i;
                    Co[(size_t)rr*N + cc] = acc[m][n][i] + resid[(size_t)rr*N + cc];
                }
            }
    } else {
        unsigned short* outp = (unsigned short*)Cout0;
        #pragma unroll
        for (int m = 0; m < 4; ++m)
            #pragma unroll
            for (int n = 0; n < 2; ++n){
                int cc = n0 + wcol*32 + n*16 + rcol;
                #pragma unroll
                for (int i = 0; i < 4; ++i){
                    int rr = m0 + wrow*64 + m*16 + rrow + i;
                    outp[(size_t)rr*N + cc] = f2bf_bits(acc[m][n][i]);
                }
            }
    }
}

// ---------------- conv(K=4)+SiLU: 8 rows per block, rolling register window ----------------
__global__ __launch_bounds__(256) void conv_silu_kernel(const unsigned short* __restrict__ xp,
                                                        const float* __restrict__ cw,
                                                        const float* __restrict__ cb,
                                                        unsigned short* __restrict__ xs){
    int bid = blockIdx.x;                          // 512 blocks
    int r0 = ((bid & 7)*64 + (bid >> 3)) * 8;
    int t0 = r0 & (SEQ - 1);
    int tid = threadIdx.x;
    int c8 = tid*8;

    float4 cwv[8];
    #pragma unroll
    for (int k = 0; k < 8; ++k) cwv[k] = ((const float4*)cw)[c8 + k];
    float cbv[8];
    {
        float4 cb0 = ((const float4*)cb)[tid*2];
        float4 cb1 = ((const float4*)cb)[tid*2+1];
        cbv[0]=cb0.x; cbv[1]=cb0.y; cbv[2]=cb0.z; cbv[3]=cb0.w;
        cbv[4]=cb1.x; cbv[5]=cb1.y; cbv[6]=cb1.z; cbv[7]=cb1.w;
    }

    ushort8v zero8 = {0,0,0,0,0,0,0,0};
    ushort8v xm3, xm2, xm1, cur, nxt;
    if (t0 >= 3){
        xm3 = *(const ushort8v*)(xp + (size_t)(r0-3)*D_INNER + c8);
        xm2 = *(const ushort8v*)(xp + (size_t)(r0-2)*D_INNER + c8);
        xm1 = *(const ushort8v*)(xp + (size_t)(r0-1)*D_INNER + c8);
    } else {
        xm3 = zero8; xm2 = zero8; xm1 = zero8;
    }
    cur = *(const ushort8v*)(xp + (size_t)r0*D_INNER + c8);

    #pragma unroll
    for (int i = 0; i < 8; ++i){
        if (i < 7) nxt = *(const ushort8v*)(xp + (size_t)(r0+i+1)*D_INNER + c8);
        ushort8v o;
        #pragma unroll
        for (int k = 0; k < 8; ++k){
            float a = cbv[k]
                    + bf2f(xm3[k])*cwv[k].x
                    + bf2f(xm2[k])*cwv[k].y
                    + bf2f(xm1[k])*cwv[k].z
                    + bf2f(cur[k])*cwv[k].w;
            o[k] = f2bf_bits(silu_f(a));
        }
        *(ushort8v*)(xs + (size_t)(r0+i)*D_INNER + c8) = o;
        xm3 = xm2; xm2 = xm1; xm1 = cur; cur = nxt;
    }
}

// ---------------- xdT: full head per block (4 d-subtiles), cached dt, emits cums ----------------
__global__ __launch_bounds__(256) void xdT_kernel(const unsigned short* __restrict__ xs,
                                                  const unsigned short* __restrict__ BCm,
                                                  const float* __restrict__ dt_b,
                                                  const float* __restrict__ A_log,
                                                  unsigned short* __restrict__ xdT,
                                                  float* __restrict__ cums){
    int ct = blockIdx.x, bh = blockIdx.y;
    int b = bh >> 3, h = bh & 7;
    __shared__ unsigned short sT[64*68];
    __shared__ float sdt[64];
    int tid = threadIdx.x;
    if (tid < 64){
        int t = ct*64 + tid;
        float raw = bf2f(BCm[(size_t)(b*SEQ + t)*BCN + 1024 + h]);
        float dtv = softplus_f(raw + dt_b[h]);
        sdt[tid] = dtv;
        float Ah = -__expf(A_log[h]);
        float a = dtv * Ah;
        #pragma unroll
        for (int i = 1; i < 64; i <<= 1){
            float v = __shfl_up(a, i);
            if (tid >= i) a += v;
        }
        cums[((size_t)bh)*SEQ + t] = a;
    }
    __syncthreads();
    for (int cd = 0; cd < 4; ++cd){
        #pragma unroll
        for (int it = 0; it < 2; ++it){
            int l = tid + it*256;
            int tl = l >> 3, seg = l & 7;
            int row = b*SEQ + ct*64 + tl;
            ushort8v v = *(const ushort8v*)(xs + (size_t)row*D_INNER + h*D_HEAD + cd*64 + seg*8);
            float dtv = sdt[tl];
            ushort4v lo, hi;
            #pragma unroll
            for (int j = 0; j < 4; ++j){
                lo[j] = f2bf_bits(bf2f(v[j]) * dtv);
                hi[j] = f2bf_bits(bf2f(v[j+4]) * dtv);
            }
            *(ushort4v*)((char*)sT + tl*136 + seg*16)     = lo;
            *(ushort4v*)((char*)sT + tl*136 + seg*16 + 8) = hi;
        }
        __syncthreads();
        #pragma unroll
        for (int it = 0; it < 2; ++it){
            int l = tid + it*256;
            int dl = l >> 3, tseg = l & 7;
            ushort8v o;
            #pragma unroll
            for (int j = 0; j < 8; ++j) o[j] = sT[(tseg*8 + j)*68 + dl];
            *(ushort8v*)(xdT + ((size_t)bh*D_HEAD + cd*64 + dl)*SEQ + ct*64 + tseg*8) = o;
        }
        __syncthreads();
    }
}

// ---------------- chunk_state (MFMA), d-split ----------------
__global__ __launch_bounds__(256) void chunk_state_mfma(const unsigned short* __restrict__ xdT,
                                                        const unsigned short* __restrict__ BCm,
                                                        const float* __restrict__ cums,
                                                        unsigned short* __restrict__ HSb){
    int c = blockIdx.x;
    int by = blockIdx.y;
    int h = by >> 1, dh = by & 1;
    int b = blockIdx.z;
    int tid = threadIdx.x;
    int bh = b*N_HEADS + h;
    int t0 = c*64;
    __shared__ unsigned short sX[128*64];
    __shared__ unsigned short sBdT[64*72];
    __shared__ float sdec[64];
    if (tid < 64)
        sdec[tid] = __expf(cums[(size_t)bh*SEQ + t0 + 63] - cums[(size_t)bh*SEQ + t0 + tid]);
    const unsigned short* xb = xdT + ((size_t)bh*D_HEAD + dh*128)*SEQ + t0;
    #pragma unroll
    for (int it = 0; it < 4; ++it){
        int l = tid + it*256;
        int d = l >> 3, seg = l & 7;
        gload_lds16(xb + (size_t)d*SEQ + (((seg*16) ^ ((d&7)<<4)) >> 1),
                    (char*)sX + (size_t)l*16);
    }
    __syncthreads();
    #pragma unroll
    for (int it = 0; it < 2; ++it){
        int l = tid + it*256;
        int tl = l >> 3, seg = l & 7;
        ushort8v bv = *(const ushort8v*)(BCm + (size_t)(b*SEQ + t0 + tl)*BCN + h*64 + seg*8);
        float dec = sdec[tl];
        #pragma unroll
        for (int j = 0; j < 8; ++j)
            sBdT[(seg*8 + j)*72 + tl] = f2bf_bits(bf2f(bv[j]) * dec);
    }
    __syncthreads();

    int lane = tid & 63, w = tid >> 6;
    int d0 = w*32;
    int fr = lane & 15, fk = (lane >> 4)*8;
    f32x4 acc[2][4];
    #pragma unroll
    for (int i = 0; i < 2; ++i)
        #pragma unroll
        for (int j = 0; j < 4; ++j) acc[i][j] = (f32x4){0.f,0.f,0.f,0.f};
    short8v af[2][2], bg[4][2];
    #pragma unroll
    for (int m = 0; m < 2; ++m)
        #pragma unroll
        for (int k = 0; k < 2; ++k){
            int d = d0 + m*16 + fr;
            af[m][k] = *(const short8v*)((const char*)sX + (size_t)d*128 + (((k*32+fk)*2) ^ ((d&7)<<4)));
        }
    #pragma unroll
    for (int n = 0; n < 4; ++n)
        #pragma unroll
        for (int k = 0; k < 2; ++k)
            bg[n][k] = *(const short8v*)(sBdT + (size_t)(n*16 + fr)*72 + k*32 + fk);
    #pragma unroll
    for (int k = 0; k < 2; ++k)
        #pragma unroll
        for (int m = 0; m < 2; ++m)
            #pragma unroll
            for (int n = 0; n < 4; ++n)
                acc[m][n] = __builtin_amdgcn_mfma_f32_16x16x32_bf16(af[m][k], bg[n][k], acc[m][n], 0, 0, 0);

    unsigned short* out = HSb + ((size_t)bh*NCHUNK + c)*16384 + (size_t)dh*128*64;
    int rr = (lane >> 4)*4, rc = lane & 15;
    #pragma unroll
    for (int m = 0; m < 2; ++m)
        #pragma unroll
        for (int n = 0; n < 4; ++n)
            #pragma unroll
            for (int i = 0; i < 4; ++i)
                out[(size_t)(d0 + m*16 + rr + i)*64 + n*16 + rc] = f2bf_bits(acc[m][n][i]);
}

// ---------------- chunk recurrence over bf16 states ----------------
__global__ __launch_bounds__(256) void state_pass_kernel(const float* __restrict__ cums,
                                                         unsigned short* __restrict__ HSb){
    int e2 = blockIdx.x*256 + threadIdx.x;
    int bh = blockIdx.y;
    float Hx = 0.f, Hy = 0.f;
    ushort2v* p = (ushort2v*)(HSb + (size_t)bh*NCHUNK*16384) + e2;
    const float* cp = cums + (size_t)bh*SEQ + 63;
    for (int c = 0; c < NCHUNK; ++c){
        float Pc = __expf(cp[(size_t)c*64]);
        ushort2v s = *p;
        float sx = bf2f(s[0]), sy = bf2f(s[1]);
        ushort2v hold;
        hold[0] = f2bf_bits(Hx); hold[1] = f2bf_bits(Hy);
        *p = hold;
        Hx = fmaf(Pc, Hx, sx);
        Hy = fmaf(Pc, Hy, sy);
        p += 8192;
    }
}

// ---------------- chunk_out (MFMA), d-split ----------------
__global__ __launch_bounds__(256) void chunk_out_mfma(const unsigned short* __restrict__ xs,
                                                      const unsigned short* __restrict__ z,
                                                      const unsigned short* __restrict__ BCm,
                                                      const unsigned short* __restrict__ xdT,
                                                      const float* __restrict__ cums,
                                                      const unsigned short* __restrict__ HSb,
                                                      const float* __restrict__ Dp,
                                                      unsigned short* __restrict__ y){
    int c = blockIdx.x;
    int by = blockIdx.y;
    int h = by >> 1, dh = by & 1;
    int b = blockIdx.z;
    int tid = threadIdx.x;
    int bh = b*N_HEADS + h;
    int t0 = c*64;
    __shared__ unsigned short regA[128*64];
    __shared__ unsigned short sW[64*64];
    __shared__ unsigned short sCd[64*64];
    __shared__ float scum[64];
    unsigned short* Craw = regA;
    unsigned short* Braw = regA + 64*64;

    if (tid < 64) scum[tid] = cums[(size_t)bh*SEQ + t0 + tid];
    #pragma unroll
    for (int it = 0; it < 2; ++it){
        int l = tid + it*256;
        int tl = l >> 3, seg = l & 7;
        size_t rowoff = (size_t)(b*SEQ + t0 + tl)*BCN + h*64;
        int soff = ((seg*16) ^ ((tl&7)<<4)) >> 1;
        gload_lds16(BCm + rowoff + 512 + soff, (char*)Craw + (size_t)l*16);
        gload_lds16(BCm + rowoff + soff,       (char*)Braw + (size_t)l*16);
    }
    __syncthreads();

    int lane = tid & 63, w = tid >> 6;
    int fr = lane & 15, fk = (lane >> 4)*8;
    int rr = (lane >> 4)*4, rc = lane & 15;

    int wr = w >> 1, wc = w & 1;
    f32x4 g[2][2];
    #pragma unroll
    for (int i = 0; i < 2; ++i)
        #pragma unroll
        for (int j = 0; j < 2; ++j) g[i][j] = (f32x4){0.f,0.f,0.f,0.f};
    {
        short8v ca[2][2], bb[2][2];
        #pragma unroll
        for (int m = 0; m < 2; ++m)
            #pragma unroll
            for (int k = 0; k < 2; ++k){
                int t = wr*32 + m*16 + fr;
                ca[m][k] = *(const short8v*)((const char*)Craw + (size_t)t*128 + (((k*32+fk)*2) ^ ((t&7)<<4)));
            }
        #pragma unroll
        for (int n = 0; n < 2; ++n)
            #pragma unroll
            for (int k = 0; k < 2; ++k){
                int s = wc*32 + n*16 + fr;
                bb[n][k] = *(const short8v*)((const char*)Braw + (size_t)s*128 + (((k*32+fk)*2) ^ ((s&7)<<4)));
            }
        #pragma unroll
        for (int k = 0; k < 2; ++k)
            #pragma unroll
            for (int m = 0; m < 2; ++m)
                #pragma unroll
                for (int n = 0; n < 2; ++n)
                    g[m][n] = __builtin_amdgcn_mfma_f32_16x16x32_bf16(ca[m][k], bb[n][k], g[m][n], 0, 0, 0);
    }
    #pragma unroll
    for (int m = 0; m < 2; ++m)
        #pragma unroll
        for (int n = 0; n < 2; ++n)
            #pragma unroll
            for (int i = 0; i < 4; ++i){
                int t = wr*32 + m*16 + rr + i;
                int s = wc*32 + n*16 + rc;
                float wv = (s <= t) ? __expf(scum[t] - scum[s]) * g[m][n][i] : 0.f;
                *(unsigned short*)((char*)sW + (size_t)t*128 + ((s*2) ^ ((t&7)<<4))) = f2bf_bits(wv);
            }
    {
        int tl = tid >> 2, sg = tid & 3;
        float ef = __expf(scum[tl]);
        #pragma unroll
        for (int q = 0; q < 2; ++q){
            int off = ((sg*32 + q*16)) ^ ((tl&7)<<4);
            ushort8v cv = *(const ushort8v*)((const char*)Craw + (size_t)tl*128 + off);
            ushort8v ov;
            #pragma unroll
            for (int j = 0; j < 8; ++j) ov[j] = f2bf_bits(bf2f(cv[j]) * ef);
            *(ushort8v*)((char*)sCd + (size_t)tl*128 + off) = ov;
        }
    }
    __syncthreads();

    const unsigned short* xb = xdT + ((size_t)bh*D_HEAD + dh*128)*SEQ + t0;
    #pragma unroll
    for (int it = 0; it < 4; ++it){
        int l = tid + it*256;
        int d = l >> 3, seg = l & 7;
        gload_lds16(xb + (size_t)d*SEQ + (((seg*16) ^ ((d&7)<<4)) >> 1),
                    (char*)regA + (size_t)l*16);
    }
    __syncthreads();

    int d0 = w*32;
    f32x4 acc[4][2];
    #pragma unroll
    for (int i = 0; i < 4; ++i)
        #pragma unroll
        for (int j = 0; j < 2; ++j) acc[i][j] = (f32x4){0.f,0.f,0.f,0.f};
    {
        short8v aw[4][2], xd[2][2];
        #pragma unroll
        for (int m = 0; m < 4; ++m)
            #pragma unroll
            for (int k = 0; k < 2; ++k){
                int t = m*16 + fr;
                aw[m][k] = *(const short8v*)((const char*)sW + (size_t)t*128 + (((k*32+fk)*2) ^ ((t&7)<<4)));
            }
        #pragma unroll
        for (int n = 0; n < 2; ++n)
            #pragma unroll
            for (int k = 0; k < 2; ++k){
                int d = d0 + n*16 + fr;
                xd[n][k] = *(const short8v*)((const char*)regA + (size_t)d*128 + (((k*32+fk)*2) ^ ((d&7)<<4)));
            }
        #pragma unroll
        for (int k = 0; k < 2; ++k)
            #pragma unroll
            for (int m = 0; m < 4; ++m)
                #pragma unroll
                for (int n = 0; n < 2; ++n)
                    acc[m][n] = __builtin_amdgcn_mfma_f32_16x16x32_bf16(aw[m][k], xd[n][k], acc[m][n], 0, 0, 0);
    }
    __syncthreads();

    const unsigned short* hb = HSb + ((size_t)bh*NCHUNK + c)*16384 + (size_t)dh*128*64;
    #pragma unroll
    for (int it = 0; it < 4; ++it){
        int l = tid + it*256;
        int d = l >> 3, seg = l & 7;
        gload_lds16(hb + (size_t)d*64 + (((seg*16) ^ ((d&7)<<4)) >> 1),
                    (char*)regA + (size_t)l*16);
    }
    __syncthreads();

    {
        short8v aw[4][2], ht[2][2];
        #pragma unroll
        for (int m = 0; m < 4; ++m)
            #pragma unroll
            for (int k = 0; k < 2; ++k){
                int t = m*16 + fr;
                aw[m][k] = *(const short8v*)((const char*)sCd + (size_t)t*128 + (((k*32+fk)*2) ^ ((t&7)<<4)));
            }
        #pragma unroll
        for (int n = 0; n < 2; ++n)
            #pragma unroll
            for (int k = 0; k < 2; ++k){
                int d = d0 + n*16 + fr;
                ht[n][k] = *(const short8v*)((const char*)regA + (size_t)d*128 + (((k*32+fk)*2) ^ ((d&7)<<4)));
            }
        #pragma unroll
        for (int k = 0; k < 2; ++k)
            #pragma unroll
            for (int m = 0; m < 4; ++m)
                #pragma unroll
                for (int n = 0; n < 2; ++n)
                    acc[m][n] = __builtin_amdgcn_mfma_f32_16x16x32_bf16(aw[m][k], ht[n][k], acc[m][n], 0, 0, 0);
    }

    float Dh = Dp[h];
    #pragma unroll
    for (int m = 0; m < 4; ++m)
        #pragma unroll
        for (int n = 0; n < 2; ++n)
            #pragma unroll
            for (int i = 0; i < 4; ++i){
                int t = m*16 + rr + i;
                int d = dh*128 + d0 + n*16 + rc;
                size_t off = (size_t)(b*SEQ + t0 + t)*D_INNER + h*D_HEAD + d;
                float val = acc[m][n][i] + Dh * bf2f(xs[off]);
                y[off] = f2bf_bits(val * silu_f(bf2f(z[off])));
            }
}

// ---------------- launch ----------------
extern "C" void kernel_launch(void* const* d_in, const int* in_sizes, int n_in,
                              void* d_out, int out_size, void* d_ws, size_t ws_size,
                              hipStream_t stream){
    const float* x      = (const float*)d_in[0];
    const float* norm_w = (const float*)d_in[1];
    const float* in_w   = (const float*)d_in[2];
    const float* conv_w = (const float*)d_in[3];
    const float* conv_b = (const float*)d_in[4];
    const float* A_log  = (const float*)d_in[5];
    const float* B_w    = (const float*)d_in[6];
    const float* C_w    = (const float*)d_in[7];
    const float* dt_w   = (const float*)d_in[8];
    const float* dt_b   = (const float*)d_in[9];
    const float* Dp     = (const float*)d_in[10];
    const float* out_w  = (const float*)d_in[11];
    float* out = (float*)d_out;

    char* ws = (char*)d_ws;
    const size_t MB = 1048576ull;
    unsigned short* xpre_bf = (unsigned short*)(ws);             // [0,16) ; reused as y
    unsigned short* y_bf    = xpre_bf;
    unsigned short* z_bf    = (unsigned short*)(ws + 16*MB);     // [16,32)
    unsigned short* xs_bf   = (unsigned short*)(ws + 32*MB);     // [32,48)
    unsigned short* inw_bf  = (unsigned short*)(ws + 48*MB);     // [48,56) dead before xdT written
    unsigned short* xdT     = (unsigned short*)(ws + 48*MB);     // [48,64)
    unsigned short* HSb     = (unsigned short*)(ws + 64*MB);     // [64,80)
    unsigned short* BCm     = (unsigned short*)(ws + 80*MB);     // [80,89.1)
    unsigned short* outw_bf = (unsigned short*)(ws + 90*MB);     // [90,94)
    unsigned short* xn_bf   = (unsigned short*)(ws + 94*MB);     // [94,102)
    unsigned short* BCw_bf  = (unsigned short*)(ws + 102*MB);    // [102,106.5)
    float*          cums    = (float*)(ws + 107*MB);             // 128 KB

    prep_kernel<<<12544, 256, 0, stream>>>(in_w, out_w, B_w, C_w, dt_w, x, norm_w,
                                           inw_bf, outw_bf, BCw_bf, xn_bf);

    gemm_in512<<<512, 512, 0, stream>>>(xn_bf, inw_bf, xpre_bf, z_bf);

    conv_silu_kernel<<<512, 256, 0, stream>>>(xpre_bf, conv_w, conv_b, xs_bf);

    gemm_k2048<0,1><<<288, 512, 0, stream>>>(xs_bf, BCw_bf, BCm, nullptr,
        ROWS, BCN, D_INNER);

    xdT_kernel<<<dim3(SEQ/64, BATCH*N_HEADS), 256, 0, stream>>>(xs_bf, BCm, dt_b, A_log, xdT, cums);

    chunk_state_mfma<<<dim3(NCHUNK, N_HEADS*2, BATCH), 256, 0, stream>>>(xdT, BCm, cums, HSb);

    state_pass_kernel<<<dim3(32, BATCH*N_HEADS), 256, 0, stream>>>(cums, HSb);

    chunk_out_mfma<<<dim3(NCHUNK, N_HEADS*2, BATCH), 256, 0, stream>>>(xs_bf, z_bf, BCm, xdT, cums, HSb, Dp, y_bf);

    gemm_k2048<2,0><<<256, 512, 0, stream>>>(y_bf, outw_bf, out, x,
        ROWS, D_MODEL, D_INNER);
}